// Round 3
// baseline (78.743 us; speedup 1.0000x reference)
//
#include <hip/hip_runtime.h>

// Lattice geometry (fixed by the reference problem)
constexpr int TD = 32, XD = 16, YD = 16, ZD = 16;
constexpr int NSITE  = TD * XD * YD * ZD;   // 131072 = 2^17
constexpr int NBATCH = 16;
constexpr int BPT    = 2;                   // batches per thread (short serial chain)
constexpr int NGROUP = NBATCH / BPT;        // 8

typedef float v4f __attribute__((ext_vector_type(4)));  // native clang vector

__global__ __launch_bounds__(256) void qshift_kernel(
    const float* __restrict__ field,   // [B, T,X,Y,Z, 3,4]
    const float* __restrict__ gauge,   // [4, T,X,Y,Z, 3,3]
    const int*   __restrict__ dir_p,   // single int
    float*       __restrict__ out)     // [B, T,X,Y,Z, 3,4]
{
    long tid = (long)blockIdx.x * blockDim.x + threadIdx.x;
    if (tid >= (long)NSITE * NGROUP) return;
    const int site = (int)(tid & (NSITE - 1));
    const int bgrp = (int)(tid >> 17);          // NSITE == 2^17
    const int b0   = bgrp * BPT;
    const int dir  = *dir_p;                    // wave-uniform

    const long fbase_site = (long)b0 * NSITE;   // in units of sites

    if (dir == 0) {
        // identity: straight copy of this thread's batches
        const v4f* src = (const v4f*)field + (fbase_site + site) * 3;
        v4f*       dst = (v4f*)out        + (fbase_site + site) * 3;
        #pragma unroll
        for (int i = 0; i < BPT; ++i) {
            const long off = (long)i * NSITE * 3;
            __builtin_nontemporal_store(src[off + 0], &dst[off + 0]);
            __builtin_nontemporal_store(src[off + 1], &dst[off + 1]);
            __builtin_nontemporal_store(src[off + 2], &dst[off + 2]);
        }
        return;
    }

    const int d = (dir > 0) ? dir : -dir;       // 1..4
    const int a = d - 1;                        // lattice axis 0..3 (T,X,Y,Z)

    // axis shift/length in the linear site index (z innermost)
    const int shift = (a == 0) ? 12 : (a == 1) ? 8 : (a == 2) ? 4 : 0;
    const int len   = (a == 0) ? TD : 16;

    const int ca = (site >> shift) & (len - 1); // this dest's coord on axis a
    int cs;                                     // source coord on axis a
    bool transpose;
    if (dir > 0) {                              // out[i] = gp[i-1]^T @ f[i-1]
        cs = (ca == 0) ? (len - 1) : (ca - 1);
        transpose = true;
    } else {                                    // out[i] = gp[i] @ f[i+1]
        cs = (ca == len - 1) ? 0 : (ca + 1);
        transpose = false;
    }
    const int srcsite = site + ((cs - ca) << shift);
    const int gsite   = (dir > 0) ? srcsite : site;

    // load 3x3 gauge (scalar loads; slice is L2/L3-resident)
    const float* gp = gauge + ((long)a * NSITE + (long)gsite) * 9;
    float g0 = gp[0], g1 = gp[1], g2 = gp[2];
    float g3 = gp[3], g4 = gp[4], g5 = gp[5];
    float g6 = gp[6], g7 = gp[7], g8 = gp[8];

    // effective matrix m[row][col]: out[c][s] = sum_cc m[c][cc] * f[cc][s]
    float m00, m01, m02, m10, m11, m12, m20, m21, m22;
    if (transpose) {
        m00 = g0; m01 = g3; m02 = g6;
        m10 = g1; m11 = g4; m12 = g7;
        m20 = g2; m21 = g5; m22 = g8;
    } else {
        m00 = g0; m01 = g1; m02 = g2;
        m10 = g3; m11 = g4; m12 = g5;
        m20 = g6; m21 = g7; m22 = g8;
    }

    const v4f* fsrc = (const v4f*)field + (fbase_site + srcsite) * 3;
    v4f*       dst  = (v4f*)out        + (fbase_site + site) * 3;

    #pragma unroll
    for (int i = 0; i < BPT; ++i) {
        const long off = (long)i * NSITE * 3;
        const v4f f0 = fsrc[off + 0];   // color 0, spins 0..3
        const v4f f1 = fsrc[off + 1];   // color 1
        const v4f f2 = fsrc[off + 2];   // color 2
        v4f o0 = m00*f0 + m01*f1 + m02*f2;
        v4f o1 = m10*f0 + m11*f1 + m12*f2;
        v4f o2 = m20*f0 + m21*f1 + m22*f2;
        __builtin_nontemporal_store(o0, &dst[off + 0]);
        __builtin_nontemporal_store(o1, &dst[off + 1]);
        __builtin_nontemporal_store(o2, &dst[off + 2]);
    }
}

extern "C" void kernel_launch(void* const* d_in, const int* in_sizes, int n_in,
                              void* d_out, int out_size, void* d_ws, size_t ws_size,
                              hipStream_t stream) {
    const float* field = (const float*)d_in[0];
    const float* gauge = (const float*)d_in[1];
    const int*   dirp  = (const int*)d_in[2];
    float*       outp  = (float*)d_out;

    const long nthreads = (long)NSITE * NGROUP;    // 1048576
    const int  block = 256;
    const int  grid  = (int)((nthreads + block - 1) / block);  // 4096
    qshift_kernel<<<grid, block, 0, stream>>>(field, gauge, dirp, outp);
}

// Round 4
// 38.084 us; speedup vs baseline: 2.0676x; 2.0676x over previous
//
#include <hip/hip_runtime.h>

// Lattice geometry (fixed by the reference problem)
constexpr int TD = 32, XD = 16, YD = 16, ZD = 16;
constexpr int NSITE  = TD * XD * YD * ZD;   // 131072 = 2^17
constexpr int NBATCH = 16;
constexpr int BPT    = 2;                   // batches per thread (short serial chain)
constexpr int NGROUP = NBATCH / BPT;        // 8

typedef float v4f __attribute__((ext_vector_type(4)));  // native clang vector

__global__ __launch_bounds__(256) void qshift_kernel(
    const float* __restrict__ field,   // [B, T,X,Y,Z, 3,4]
    const float* __restrict__ gauge,   // [4, T,X,Y,Z, 3,3]
    const int*   __restrict__ dir_p,   // single int
    float*       __restrict__ out)     // [B, T,X,Y,Z, 3,4]
{
    long tid = (long)blockIdx.x * blockDim.x + threadIdx.x;
    if (tid >= (long)NSITE * NGROUP) return;
    const int site = (int)(tid & (NSITE - 1));
    const int bgrp = (int)(tid >> 17);          // NSITE == 2^17
    const int b0   = bgrp * BPT;
    const int dir  = *dir_p;                    // wave-uniform

    const long fbase_site = (long)b0 * NSITE;   // in units of sites

    if (dir == 0) {
        // identity: straight copy of this thread's batches
        const v4f* src = (const v4f*)field + (fbase_site + site) * 3;
        v4f*       dst = (v4f*)out        + (fbase_site + site) * 3;
        #pragma unroll
        for (int i = 0; i < BPT; ++i) {
            const long off = (long)i * NSITE * 3;
            dst[off + 0] = src[off + 0];
            dst[off + 1] = src[off + 1];
            dst[off + 2] = src[off + 2];
        }
        return;
    }

    const int d = (dir > 0) ? dir : -dir;       // 1..4
    const int a = d - 1;                        // lattice axis 0..3 (T,X,Y,Z)

    // axis shift/length in the linear site index (z innermost)
    const int shift = (a == 0) ? 12 : (a == 1) ? 8 : (a == 2) ? 4 : 0;
    const int len   = (a == 0) ? TD : 16;

    const int ca = (site >> shift) & (len - 1); // this dest's coord on axis a
    int cs;                                     // source coord on axis a
    bool transpose;
    if (dir > 0) {                              // out[i] = gp[i-1]^T @ f[i-1]
        cs = (ca == 0) ? (len - 1) : (ca - 1);
        transpose = true;
    } else {                                    // out[i] = gp[i] @ f[i+1]
        cs = (ca == len - 1) ? 0 : (ca + 1);
        transpose = false;
    }
    const int srcsite = site + ((cs - ca) << shift);
    const int gsite   = (dir > 0) ? srcsite : site;

    // load 3x3 gauge (scalar loads; slice is L2/L3-resident)
    const float* gp = gauge + ((long)a * NSITE + (long)gsite) * 9;
    float g0 = gp[0], g1 = gp[1], g2 = gp[2];
    float g3 = gp[3], g4 = gp[4], g5 = gp[5];
    float g6 = gp[6], g7 = gp[7], g8 = gp[8];

    // effective matrix m[row][col]: out[c][s] = sum_cc m[c][cc] * f[cc][s]
    float m00, m01, m02, m10, m11, m12, m20, m21, m22;
    if (transpose) {
        m00 = g0; m01 = g3; m02 = g6;
        m10 = g1; m11 = g4; m12 = g7;
        m20 = g2; m21 = g5; m22 = g8;
    } else {
        m00 = g0; m01 = g1; m02 = g2;
        m10 = g3; m11 = g4; m12 = g5;
        m20 = g6; m21 = g7; m22 = g8;
    }

    const v4f* fsrc = (const v4f*)field + (fbase_site + srcsite) * 3;
    v4f*       dst  = (v4f*)out        + (fbase_site + site) * 3;

    #pragma unroll
    for (int i = 0; i < BPT; ++i) {
        const long off = (long)i * NSITE * 3;
        const v4f f0 = fsrc[off + 0];   // color 0, spins 0..3
        const v4f f1 = fsrc[off + 1];   // color 1
        const v4f f2 = fsrc[off + 2];   // color 2
        dst[off + 0] = m00*f0 + m01*f1 + m02*f2;
        dst[off + 1] = m10*f0 + m11*f1 + m12*f2;
        dst[off + 2] = m20*f0 + m21*f1 + m22*f2;
    }
}

extern "C" void kernel_launch(void* const* d_in, const int* in_sizes, int n_in,
                              void* d_out, int out_size, void* d_ws, size_t ws_size,
                              hipStream_t stream) {
    const float* field = (const float*)d_in[0];
    const float* gauge = (const float*)d_in[1];
    const int*   dirp  = (const int*)d_in[2];
    float*       outp  = (float*)d_out;

    const long nthreads = (long)NSITE * NGROUP;    // 1048576
    const int  block = 256;
    const int  grid  = (int)((nthreads + block - 1) / block);  // 4096
    qshift_kernel<<<grid, block, 0, stream>>>(field, gauge, dirp, outp);
}

// Round 5
// 37.944 us; speedup vs baseline: 2.0752x; 1.0037x over previous
//
#include <hip/hip_runtime.h>

// Lattice geometry (fixed by the reference problem)
constexpr int TD = 32, XD = 16, YD = 16, ZD = 16;
constexpr int NSITE  = TD * XD * YD * ZD;   // 131072 = 2^17
constexpr int NBATCH = 16;
constexpr int BPT    = 2;                   // batches per thread (short serial chain)
constexpr int NGROUP = NBATCH / BPT;        // 8

typedef float v4f  __attribute__((ext_vector_type(4)));              // 16B-aligned
typedef float v4fu __attribute__((ext_vector_type(4), aligned(4)));  // 4B-aligned view

__global__ __launch_bounds__(256) void qshift_kernel(
    const float* __restrict__ field,   // [B, T,X,Y,Z, 3,4]
    const float* __restrict__ gauge,   // [4, T,X,Y,Z, 3,3]
    const int*   __restrict__ dir_p,   // single int
    float*       __restrict__ out)     // [B, T,X,Y,Z, 3,4]
{
    long tid = (long)blockIdx.x * blockDim.x + threadIdx.x;
    if (tid >= (long)NSITE * NGROUP) return;
    const int site = (int)(tid & (NSITE - 1));
    const int bgrp = (int)(tid >> 17);          // NSITE == 2^17
    const int b0   = bgrp * BPT;
    const int dir  = *dir_p;                    // wave-uniform

    const long fbase_site = (long)b0 * NSITE;   // in units of sites

    if (dir == 0) {
        // identity: straight copy of this thread's batches
        const v4f* src = (const v4f*)field + (fbase_site + site) * 3;
        v4f*       dst = (v4f*)out        + (fbase_site + site) * 3;
        #pragma unroll
        for (int i = 0; i < BPT; ++i) {
            const long off = (long)i * NSITE * 3;
            dst[off + 0] = src[off + 0];
            dst[off + 1] = src[off + 1];
            dst[off + 2] = src[off + 2];
        }
        return;
    }

    const int d = (dir > 0) ? dir : -dir;       // 1..4
    const int a = d - 1;                        // lattice axis 0..3 (T,X,Y,Z)

    // axis shift/length in the linear site index (z innermost)
    const int shift = (a == 0) ? 12 : (a == 1) ? 8 : (a == 2) ? 4 : 0;
    const int len   = (a == 0) ? TD : 16;

    const int ca = (site >> shift) & (len - 1); // this dest's coord on axis a
    int cs;                                     // source coord on axis a
    bool transpose;
    if (dir > 0) {                              // out[i] = gp[i-1]^T @ f[i-1]
        cs = (ca == 0) ? (len - 1) : (ca - 1);
        transpose = true;
    } else {                                    // out[i] = gp[i] @ f[i+1]
        cs = (ca == len - 1) ? 0 : (ca + 1);
        transpose = false;
    }
    const int srcsite = site + ((cs - ca) << shift);
    const int gsite   = (dir > 0) ? srcsite : site;

    // load 3x3 gauge as 2x dwordx4 + 1 dword (4B-aligned vector loads)
    const float* gp = gauge + ((long)a * NSITE + (long)gsite) * 9;
    const v4fu ga = *(const v4fu*)(gp + 0);   // g0..g3
    const v4fu gb = *(const v4fu*)(gp + 4);   // g4..g7
    const float g8 = gp[8];
    const float g0 = ga.x, g1 = ga.y, g2 = ga.z, g3 = ga.w;
    const float g4 = gb.x, g5 = gb.y, g6 = gb.z, g7 = gb.w;

    // effective matrix m[row][col]: out[c][s] = sum_cc m[c][cc] * f[cc][s]
    float m00, m01, m02, m10, m11, m12, m20, m21, m22;
    if (transpose) {
        m00 = g0; m01 = g3; m02 = g6;
        m10 = g1; m11 = g4; m12 = g7;
        m20 = g2; m21 = g5; m22 = g8;
    } else {
        m00 = g0; m01 = g1; m02 = g2;
        m10 = g3; m11 = g4; m12 = g5;
        m20 = g6; m21 = g7; m22 = g8;
    }

    const v4f* fsrc = (const v4f*)field + (fbase_site + srcsite) * 3;
    v4f*       dst  = (v4f*)out        + (fbase_site + site) * 3;

    #pragma unroll
    for (int i = 0; i < BPT; ++i) {
        const long off = (long)i * NSITE * 3;
        const v4f f0 = fsrc[off + 0];   // color 0, spins 0..3
        const v4f f1 = fsrc[off + 1];   // color 1
        const v4f f2 = fsrc[off + 2];   // color 2
        dst[off + 0] = m00*f0 + m01*f1 + m02*f2;
        dst[off + 1] = m10*f0 + m11*f1 + m12*f2;
        dst[off + 2] = m20*f0 + m21*f1 + m22*f2;
    }
}

extern "C" void kernel_launch(void* const* d_in, const int* in_sizes, int n_in,
                              void* d_out, int out_size, void* d_ws, size_t ws_size,
                              hipStream_t stream) {
    const float* field = (const float*)d_in[0];
    const float* gauge = (const float*)d_in[1];
    const int*   dirp  = (const int*)d_in[2];
    float*       outp  = (float*)d_out;

    const long nthreads = (long)NSITE * NGROUP;    // 1048576
    const int  block = 256;
    const int  grid  = (int)((nthreads + block - 1) / block);  // 4096
    qshift_kernel<<<grid, block, 0, stream>>>(field, gauge, dirp, outp);
}